// Round 1
// baseline (1066.450 us; speedup 1.0000x reference)
//
#include <hip/hip_runtime.h>

namespace {

constexpr int kB = 4096;
constexpr int kT = 2048;
constexpr int kH = 32;
constexpr int kRowsPerBlock = 8;   // 8 groups of 32 lanes = 256 threads
constexpr int kXT = 64;            // x staging tile (timesteps)

typedef float4 f4a __attribute__((may_alias));

__device__ __forceinline__ float fast_tanh(float x) {
  // tanh(x) = 1 - 2/(exp(2x)+1); exp via exp2, ~1ulp each
  float e = __builtin_amdgcn_exp2f(x * 2.885390081777926815f); // 2*log2(e)
  float r = __builtin_amdgcn_rcpf(e + 1.0f);
  return fmaf(-2.0f, r, 1.0f);
}

template <int CTRL>
__device__ __forceinline__ float dpp_add(float x) {
  int xi = __builtin_bit_cast(int, x);
  int ri = __builtin_amdgcn_update_dpp(0, xi, CTRL, 0xF, 0xF, true);
  return x + __builtin_bit_cast(float, ri);
}

} // namespace

extern "C" __global__ __launch_bounds__(256, 2) void rnn2_fp32(
    const float* __restrict__ x,
    const float* __restrict__ w_ih0,
    const float* __restrict__ w_hh0,
    const float* __restrict__ b_ih0,
    const float* __restrict__ b_hh0,
    const float* __restrict__ w_ih1,
    const float* __restrict__ w_hh1,
    const float* __restrict__ b_ih1,
    const float* __restrict__ b_hh1,
    const float* __restrict__ w_out,
    const float* __restrict__ b_out,
    float* __restrict__ out) {
  const int tid = (int)threadIdx.x;
  const int j = tid & 31;        // output element this lane owns
  const int g = tid >> 5;        // 32-lane group id within block (one batch row)
  const int row = (int)blockIdx.x * kRowsPerBlock + g;

  __shared__ float xs[kRowsPerBlock][kXT];
  __shared__ float hsh[kRowsPerBlock][kH];

  // Per-lane weight rows (row j of each matrix). y = h @ W.T -> y[j] = sum_k W[j][k] h[k]
  float whh0[kH], wih1r[kH], whh1r[kH];
  {
    const float* p0 = w_hh0 + j * kH;
    const float* p1 = w_ih1 + j * kH;
    const float* p2 = w_hh1 + j * kH;
#pragma unroll
    for (int q = 0; q < kH / 4; ++q) {
      f4a a = *reinterpret_cast<const f4a*>(p0 + 4 * q);
      f4a b = *reinterpret_cast<const f4a*>(p1 + 4 * q);
      f4a c = *reinterpret_cast<const f4a*>(p2 + 4 * q);
      whh0[4 * q + 0] = a.x; whh0[4 * q + 1] = a.y;
      whh0[4 * q + 2] = a.z; whh0[4 * q + 3] = a.w;
      wih1r[4 * q + 0] = b.x; wih1r[4 * q + 1] = b.y;
      wih1r[4 * q + 2] = b.z; wih1r[4 * q + 3] = b.w;
      whh1r[4 * q + 0] = c.x; whh1r[4 * q + 1] = c.y;
      whh1r[4 * q + 2] = c.z; whh1r[4 * q + 3] = c.w;
    }
  }
  const float wih0_j = w_ih0[j];           // w_ih0 is [H,1]
  const float c0 = b_ih0[j] + b_hh0[j];
  const float c1 = b_ih1[j] + b_hh1[j];
  const float wout_j = w_out[j];           // w_out is [1,H]
  const float bout = b_out[0];

  // Replicated hidden state (every lane holds the full 32-vectors)
  float h0[kH], h1[kH];
#pragma unroll
  for (int k = 0; k < kH; ++k) {
    h0[k] = 0.f;
    h1[k] = 0.f;
  }

  const float* xrow = x + (long)row * kT;
  float* orow = out + (long)row * kT;
  float outval = 0.f;

  for (int t0 = 0; t0 < kT; t0 += kXT) {
    // Stage x tile for this wave's own row (within-wave, no block barrier needed)
    xs[g][j] = xrow[t0 + j];
    xs[g][32 + j] = xrow[t0 + 32 + j];
    asm volatile("s_waitcnt lgkmcnt(0) vmcnt(0)" ::: "memory");

    for (int tt = 0; tt < kXT; ++tt) {
      const float xt = xs[g][tt]; // broadcast read

      // ---------- layer 0: h0 = tanh(x*w_ih0 + c0 + W_hh0 @ h0) ----------
      float a0 = fmaf(xt, wih0_j, c0);
      float a1 = 0.f, a2 = 0.f, a3 = 0.f;
#pragma unroll
      for (int k = 0; k < kH; k += 4) {
        a0 = fmaf(whh0[k + 0], h0[k + 0], a0);
        a1 = fmaf(whh0[k + 1], h0[k + 1], a1);
        a2 = fmaf(whh0[k + 2], h0[k + 2], a2);
        a3 = fmaf(whh0[k + 3], h0[k + 3], a3);
      }
      const float h0n = fast_tanh((a0 + a1) + (a2 + a3));

      // all-gather h0new across the 32-lane group
      hsh[g][j] = h0n;
      asm volatile("s_waitcnt lgkmcnt(0)" ::: "memory");
#pragma unroll
      for (int q = 0; q < kH / 4; ++q) {
        f4a v = *reinterpret_cast<const f4a*>(&hsh[g][4 * q]);
        h0[4 * q + 0] = v.x; h0[4 * q + 1] = v.y;
        h0[4 * q + 2] = v.z; h0[4 * q + 3] = v.w;
      }

      // ---------- layer 1: h1 = tanh(W_ih1 @ h0new + c1 + W_hh1 @ h1) ----------
      float b0v = c1, b1v = 0.f, b2v = 0.f, b3v = 0.f;
#pragma unroll
      for (int k = 0; k < kH; k += 4) {
        b0v = fmaf(wih1r[k + 0], h0[k + 0], b0v);
        b1v = fmaf(wih1r[k + 1], h0[k + 1], b1v);
        b2v = fmaf(wih1r[k + 2], h0[k + 2], b2v);
        b3v = fmaf(wih1r[k + 3], h0[k + 3], b3v);
      }
#pragma unroll
      for (int k = 0; k < kH; k += 4) {
        b0v = fmaf(whh1r[k + 0], h1[k + 0], b0v);
        b1v = fmaf(whh1r[k + 1], h1[k + 1], b1v);
        b2v = fmaf(whh1r[k + 2], h1[k + 2], b2v);
        b3v = fmaf(whh1r[k + 3], h1[k + 3], b3v);
      }
      const float h1n = fast_tanh((b0v + b1v) + (b2v + b3v));

      // issue h1 gather write early; butterfly-out overlaps its latency
      hsh[g][j] = h1n;

      // ---------- out_t = w_out . h1new + b_out (reduce over 32-lane group) ----
      float o = wout_j * h1n;
      o = dpp_add<0x121>(o); // row_ror:1
      o = dpp_add<0x122>(o); // row_ror:2
      o = dpp_add<0x124>(o); // row_ror:4
      o = dpp_add<0x128>(o); // row_ror:8  -> sum within each 16-lane row
      {
        int si = __builtin_amdgcn_ds_swizzle(__builtin_bit_cast(int, o), 0x401F); // xor 16
        o += __builtin_bit_cast(float, si);
      }
      o += bout;
      outval = (j == (tt & 31)) ? o : outval; // lane (t%32) keeps step t's output

      asm volatile("s_waitcnt lgkmcnt(0)" ::: "memory");
#pragma unroll
      for (int q = 0; q < kH / 4; ++q) {
        f4a v = *reinterpret_cast<const f4a*>(&hsh[g][4 * q]);
        h1[4 * q + 0] = v.x; h1[4 * q + 1] = v.y;
        h1[4 * q + 2] = v.z; h1[4 * q + 3] = v.w;
      }

      if ((tt & 31) == 31) {
        // coalesced 128B flush: lane j holds out for t = base + j
        orow[t0 + (tt & ~31) + j] = outval;
      }
    }
  }
}

extern "C" void kernel_launch(void* const* d_in, const int* in_sizes, int n_in,
                              void* d_out, int out_size, void* d_ws, size_t ws_size,
                              hipStream_t stream) {
  (void)in_sizes; (void)n_in; (void)d_ws; (void)ws_size; (void)out_size;
  const float* xp = (const float*)d_in[0];
  const float* w_ih0 = (const float*)d_in[1];
  const float* w_hh0 = (const float*)d_in[2];
  const float* b_ih0 = (const float*)d_in[3];
  const float* b_hh0 = (const float*)d_in[4];
  const float* w_ih1 = (const float*)d_in[5];
  const float* w_hh1 = (const float*)d_in[6];
  const float* b_ih1 = (const float*)d_in[7];
  const float* b_hh1 = (const float*)d_in[8];
  const float* w_out = (const float*)d_in[9];
  const float* b_out = (const float*)d_in[10];
  // d_in[11] = future (always 0 in this harness)

  dim3 grid(kB / kRowsPerBlock); // 512 blocks
  dim3 block(kRowsPerBlock * 32);
  hipLaunchKernelGGL(rnn2_fp32, grid, block, 0, stream,
                     xp, w_ih0, w_hh0, b_ih0, b_hh0,
                     w_ih1, w_hh1, b_ih1, b_hh1,
                     w_out, b_out, (float*)d_out);
}